// Round 1
// baseline (640.159 us; speedup 1.0000x reference)
//
#include <hip/hip_runtime.h>
#include <math.h>

#define NQ     8
#define DIM    256
#define LAYERS 3
#define COUT   8
#define NB     32
#define OH     31
#define OW     31
#define NPATCH (NB*OH*OW)   // 30752

__device__ __forceinline__ float2 cmul(float2 a, float2 b) {
    return make_float2(a.x*b.x - a.y*b.y, a.x*b.y + a.y*b.x);
}
__device__ __forceinline__ void cmac(float2& c, float2 a, float2 b) {
    c.x = fmaf(a.x, b.x, fmaf(-a.y, b.y, c.x));
    c.y = fmaf(a.x, b.y, fmaf( a.y, b.x, c.y));
}

// CNOT-ring permutation: rho(i) = p0(p1(...p7(i)...)), p_q: if ctrl bit(7-q) set, flip bit(7-((q+1)%8))
__device__ __forceinline__ int rho(int i) {
    #pragma unroll
    for (int q = 7; q >= 0; --q) {
        int t = (q + 1) & 7;
        if ((i >> (7 - q)) & 1) i ^= 1 << (7 - t);
    }
    return i;
}

// ---- 1. per-(c,l,q) 2x2 rotation matrices ----------------------------------
__global__ void prep_gates(const float* __restrict__ w, float2* __restrict__ gates) {
    int tid = blockIdx.x * blockDim.x + threadIdx.x;
    if (tid >= COUT * LAYERS * NQ) return;
    float phi = w[tid*3+0], th = w[tid*3+1], om = w[tid*3+2];
    float cth = cosf(th * 0.5f), sth = sinf(th * 0.5f);
    float a = 0.5f * (phi + om), b = 0.5f * (phi - om);
    float sa, ca, sb, cb;
    sincosf(a, &sa, &ca);
    sincosf(b, &sb, &cb);
    gates[tid*4+0] = make_float2( cth*ca, -cth*sa);   // m00
    gates[tid*4+1] = make_float2(-sth*cb, -sth*sb);   // m01
    gates[tid*4+2] = make_float2( sth*cb, -sth*sb);   // m10
    gates[tid*4+3] = make_float2( cth*ca,  cth*sa);   // m11
}

// ---- 2. layer Kronecker matrices K[cl][i][j] = prod_q m_q[i_q][j_q] --------
__global__ void build_K(const float2* __restrict__ gates, float2* __restrict__ K) {
    int tid = blockIdx.x * 256 + threadIdx.x;     // 24*65536 elements
    int cl = tid >> 16;
    int e  = tid & 65535;
    int i = e >> 8, j = e & 255;
    const float2* g = gates + cl * NQ * 4;
    float2 acc = make_float2(1.f, 0.f);
    #pragma unroll
    for (int q = 0; q < 8; ++q) {
        int iq = (i >> (7 - q)) & 1, jq = (j >> (7 - q)) & 1;
        acc = cmul(acc, g[q*4 + iq*2 + jq]);
    }
    K[tid] = acc;
}

// ---- 3. complex GEMM  C = A * perm_rows(B) ---------------------------------
__global__ __launch_bounds__(256) void gemm_pb(float2* __restrict__ C,
                                               const float2* __restrict__ A,
                                               const float2* __restrict__ B,
                                               int strideC, int strideA, int strideB) {
    int ch = blockIdx.z;
    const float2* Ac = A + (size_t)ch * strideA;
    const float2* Bc = B + (size_t)ch * strideB;
    float2* Cc = C + (size_t)ch * strideC;
    int jb = blockIdx.x * 32, ib = blockIdx.y * 32;
    int t = threadIdx.x;
    int tx = t & 15, ty = t >> 4;
    __shared__ float2 As[32][33], Bs[32][33];
    float2 a00={0,0}, a01={0,0}, a10={0,0}, a11={0,0};
    for (int kb = 0; kb < 256; kb += 32) {
        __syncthreads();
        #pragma unroll
        for (int e2 = 0; e2 < 4; ++e2) {
            int idx = t + e2*256; int r = idx >> 5, cc = idx & 31;
            As[r][cc] = Ac[(ib + r)*256 + kb + cc];
            Bs[r][cc] = Bc[rho(kb + r)*256 + jb + cc];
        }
        __syncthreads();
        #pragma unroll
        for (int kk = 0; kk < 32; ++kk) {
            float2 x0 = As[ty*2][kk], x1 = As[ty*2+1][kk];
            float2 y0 = Bs[kk][tx*2], y1 = Bs[kk][tx*2+1];
            cmac(a00, x0, y0); cmac(a01, x0, y1);
            cmac(a10, x1, y0); cmac(a11, x1, y1);
        }
    }
    Cc[(ib+ty*2  )*256 + jb+tx*2  ] = a00;
    Cc[(ib+ty*2  )*256 + jb+tx*2+1] = a01;
    Cc[(ib+ty*2+1)*256 + jb+tx*2  ] = a10;
    Cc[(ib+ty*2+1)*256 + jb+tx*2+1] = a11;
}

// ---- 4. M_re[i][j] = sum_k sign(k) * Re( conj(W[rho(k)][i]) W[rho(k)][j] ) --
__global__ __launch_bounds__(256) void build_M(float* __restrict__ ReM,
                                               const float2* __restrict__ W) {
    int ch = blockIdx.z;
    const float2* Wc = W + (size_t)ch * 65536;
    float* Mc = ReM + (size_t)ch * 65536;
    int jb = blockIdx.x * 32, ib = blockIdx.y * 32;
    int t = threadIdx.x;
    int tx = t & 15, ty = t >> 4;
    __shared__ float2 WsI[32][33], WsJ[32][33];
    float a00=0, a01=0, a10=0, a11=0;
    for (int kb = 0; kb < 256; kb += 32) {
        __syncthreads();
        #pragma unroll
        for (int e2 = 0; e2 < 4; ++e2) {
            int idx = t + e2*256; int r = idx >> 5, cc = idx & 31;
            int krow = rho(kb + r);
            float sgn = ((kb + r) & 128) ? -1.f : 1.f;
            float2 wi = Wc[krow*256 + ib + cc];
            WsI[r][cc] = make_float2(wi.x*sgn, wi.y*sgn);
            WsJ[r][cc] = Wc[krow*256 + jb + cc];
        }
        __syncthreads();
        #pragma unroll
        for (int kk = 0; kk < 32; ++kk) {
            float2 i0 = WsI[kk][ty*2], i1 = WsI[kk][ty*2+1];
            float2 j0 = WsJ[kk][tx*2], j1 = WsJ[kk][tx*2+1];
            a00 = fmaf(i0.x, j0.x, fmaf(i0.y, j0.y, a00));
            a01 = fmaf(i0.x, j1.x, fmaf(i0.y, j1.y, a01));
            a10 = fmaf(i1.x, j0.x, fmaf(i1.y, j0.y, a10));
            a11 = fmaf(i1.x, j1.x, fmaf(i1.y, j1.y, a11));
        }
    }
    Mc[(ib+ty*2  )*256 + jb+tx*2  ] = a00;
    Mc[(ib+ty*2  )*256 + jb+tx*2+1] = a01;
    Mc[(ib+ty*2+1)*256 + jb+tx*2  ] = a10;
    Mc[(ib+ty*2+1)*256 + jb+tx*2+1] = a11;
}

// ---- 5. patch extraction + normalization -----------------------------------
__global__ __launch_bounds__(256) void extract(const float* __restrict__ x,
                                               float* __restrict__ sG) {
    int p = blockIdx.x;           // 0..30751
    int k = threadIdx.x;          // 0..255
    int b = p / (OH*OW); int r = p % (OH*OW);
    int oi = r / OW, oj = r % OW;
    int ci = k >> 4, fi = (k >> 2) & 3, fj = k & 3;
    float v = x[(((size_t)(b*16 + ci))*64 + (oi*2 + fi))*64 + (oj*2 + fj)];
    float ss = v * v;
    #pragma unroll
    for (int m = 1; m < 64; m <<= 1) ss += __shfl_xor(ss, m, 64);
    __shared__ float wsum[4];
    if ((k & 63) == 0) wsum[k >> 6] = ss;
    __syncthreads();
    float tot = wsum[0] + wsum[1] + wsum[2] + wsum[3];
    float inv = tot > 0.f ? 1.f / sqrtf(tot) : 0.f;
    sG[(size_t)p*256 + k] = v * inv;
}

// ---- 6. quadratic form: out = s^T ReM s + bias -----------------------------
__global__ __launch_bounds__(256) void quadform(const float* __restrict__ sG,
                                                const float* __restrict__ ReM,
                                                const float* __restrict__ bias,
                                                float* __restrict__ out) {
    int t = threadIdx.x;
    int u = t & 31;          // j-slice owner: j in [u*8, u*8+8)
    int pg = t >> 5;         // patch group (4 patches each)
    int c = blockIdx.y;
    int pbase = blockIdx.x * 32;
    const float* Mc = ReM + (size_t)c * 65536;
    __shared__ float sT[32][264];
    __shared__ float Mt[8][264];
    // cooperative load of 32 patches (32x256 floats)
    #pragma unroll
    for (int e = 0; e < 8; ++e) {
        int f = t + e*256;                 // float4 index, 2048 total
        int row = f >> 6, c4 = f & 63;
        *(float4*)&sT[row][c4*4] = *(const float4*)&sG[((size_t)(pbase+row))*256 + c4*4];
    }
    __syncthreads();
    float4 sa[4], sb[4];
    #pragma unroll
    for (int pp = 0; pp < 4; ++pp) {
        sa[pp] = *(float4*)&sT[pg*4+pp][u*8];
        sb[pp] = *(float4*)&sT[pg*4+pp][u*8+4];
    }
    float acc[4] = {0.f, 0.f, 0.f, 0.f};
    for (int ib = 0; ib < 256; ib += 8) {
        __syncthreads();
        #pragma unroll
        for (int e = 0; e < 2; ++e) {
            int f = t + e*256;             // 512 float4
            int r = f >> 6, c4 = f & 63;
            *(float4*)&Mt[r][c4*4] = *(const float4*)&Mc[(ib+r)*256 + c4*4];
        }
        __syncthreads();
        #pragma unroll
        for (int ii = 0; ii < 8; ++ii) {
            float4 m0 = *(float4*)&Mt[ii][u*8];
            float4 m1 = *(float4*)&Mt[ii][u*8+4];
            int i = ib + ii;
            #pragma unroll
            for (int pp = 0; pp < 4; ++pp) {
                float y;
                y = m0.x*sa[pp].x;
                y = fmaf(m0.y, sa[pp].y, y);
                y = fmaf(m0.z, sa[pp].z, y);
                y = fmaf(m0.w, sa[pp].w, y);
                y = fmaf(m1.x, sb[pp].x, y);
                y = fmaf(m1.y, sb[pp].y, y);
                y = fmaf(m1.z, sb[pp].z, y);
                y = fmaf(m1.w, sb[pp].w, y);
                acc[pp] = fmaf(sT[pg*4+pp][i], y, acc[pp]);
            }
        }
    }
    #pragma unroll
    for (int pp = 0; pp < 4; ++pp) {
        float v = acc[pp];
        #pragma unroll
        for (int m = 1; m < 32; m <<= 1) v += __shfl_xor(v, m, 64);
        if (u == 0) {
            int p = pbase + pg*4 + pp;
            int b = p / (OH*OW); int r2 = p % (OH*OW);
            int oi = r2 / OW, oj = r2 % OW;
            out[(((size_t)(b*COUT + c))*OH + oi)*OW + oj] = v + bias[c];
        }
    }
}

extern "C" void kernel_launch(void* const* d_in, const int* in_sizes, int n_in,
                              void* d_out, int out_size, void* d_ws, size_t ws_size,
                              hipStream_t stream) {
    const float* x    = (const float*)d_in[0];
    const float* w    = (const float*)d_in[1];
    const float* bias = (const float*)d_in[2];
    float* out = (float*)d_out;

    // workspace layout (bytes)
    const size_t OFF_GATES = 0;                         //   6144 B (pad 8192)
    const size_t OFF_K     = 8192;                      // 24*65536 float2 = 12,582,912
    const size_t OFF_T1    = OFF_K  + 12582912;         //  8*65536 float2 =  4,194,304
    const size_t OFF_T2    = OFF_T1 + 4194304;          //  4,194,304
    const size_t OFF_REM   = OFF_T2 + 4194304;          //  8*65536 float  =  2,097,152
    const size_t OFF_SG    = OFF_REM + 2097152;         // 30752*256 float = 31,490,048
    const size_t TOTAL     = OFF_SG + 31490048;
    if (ws_size < TOTAL) return;   // insufficient scratch -> fail loudly (poisoned out)

    char* ws = (char*)d_ws;
    float2* gates = (float2*)(ws + OFF_GATES);
    float2* K     = (float2*)(ws + OFF_K);
    float2* T1    = (float2*)(ws + OFF_T1);
    float2* T2    = (float2*)(ws + OFF_T2);
    float*  ReM   = (float*)(ws + OFF_REM);
    float*  sG    = (float*)(ws + OFF_SG);

    prep_gates<<<1, 256, 0, stream>>>(w, gates);
    build_K<<<(COUT*LAYERS*65536)/256, 256, 0, stream>>>(gates, K);
    // T1[c] = K1[c] * P K0[c]
    gemm_pb<<<dim3(8,8,COUT), 256, 0, stream>>>(T1, K + 65536, K, 65536, 3*65536, 3*65536);
    // T2[c] = K2[c] * P T1[c]
    gemm_pb<<<dim3(8,8,COUT), 256, 0, stream>>>(T2, K + 2*65536, T1, 65536, 3*65536, 65536);
    // ReM[c] = Re( (P T2)^H S (P T2) )
    build_M<<<dim3(8,8,COUT), 256, 0, stream>>>(ReM, T2);
    extract<<<NPATCH, 256, 0, stream>>>(x, sG);
    quadform<<<dim3(NPATCH/32, COUT), 256, 0, stream>>>(sG, ReM, bias, out);
}

// Round 2
// 166.073 us; speedup vs baseline: 3.8547x; 3.8547x over previous
//
#include <hip/hip_runtime.h>
#include <math.h>

#define NQ     8
#define DIM    256
#define LAYERS 3
#define COUT   8
#define NB     32
#define OH     31
#define OW     31
#define NPATCH (NB*OH*OW)   // 30752
#define PT_BLK 512          // patches per fused block
#define NTILE  61           // ceil(30752/512)
#define PTOT   (NTILE*PT_BLK) // 31232 (zero-padded)

typedef _Float16 f16x8 __attribute__((ext_vector_type(8)));
typedef _Float16 f16x4 __attribute__((ext_vector_type(4)));
typedef float    f32x4 __attribute__((ext_vector_type(4)));

__device__ __forceinline__ float2 cmul(float2 a, float2 b) {
    return make_float2(a.x*b.x - a.y*b.y, a.x*b.y + a.y*b.x);
}
__device__ __forceinline__ void cmac(float2& c, float2 a, float2 b) {
    c.x = fmaf(a.x, b.x, fmaf(-a.y, b.y, c.x));
    c.y = fmaf(a.x, b.y, fmaf( a.y, b.x, c.y));
}

// CNOT-ring permutation
__device__ __forceinline__ int rho(int i) {
    #pragma unroll
    for (int q = 7; q >= 0; --q) {
        int t = (q + 1) & 7;
        if ((i >> (7 - q)) & 1) i ^= 1 << (7 - t);
    }
    return i;
}

// ---- 1. per-(c,l,q) 2x2 rotation matrices ----------------------------------
__global__ void prep_gates(const float* __restrict__ w, float2* __restrict__ gates) {
    int tid = blockIdx.x * blockDim.x + threadIdx.x;
    if (tid >= COUT * LAYERS * NQ) return;
    float phi = w[tid*3+0], th = w[tid*3+1], om = w[tid*3+2];
    float cth = cosf(th * 0.5f), sth = sinf(th * 0.5f);
    float a = 0.5f * (phi + om), b = 0.5f * (phi - om);
    float sa, ca, sb, cb;
    sincosf(a, &sa, &ca);
    sincosf(b, &sb, &cb);
    gates[tid*4+0] = make_float2( cth*ca, -cth*sa);
    gates[tid*4+1] = make_float2(-sth*cb, -sth*sb);
    gates[tid*4+2] = make_float2( sth*cb, -sth*sb);
    gates[tid*4+3] = make_float2( cth*ca,  cth*sa);
}

// ---- 2. layer Kronecker matrices -------------------------------------------
__global__ void build_K(const float2* __restrict__ gates, float2* __restrict__ K) {
    int tid = blockIdx.x * 256 + threadIdx.x;
    int cl = tid >> 16;
    int e  = tid & 65535;
    int i = e >> 8, j = e & 255;
    const float2* g = gates + cl * NQ * 4;
    float2 acc = make_float2(1.f, 0.f);
    #pragma unroll
    for (int q = 0; q < 8; ++q) {
        int iq = (i >> (7 - q)) & 1, jq = (j >> (7 - q)) & 1;
        acc = cmul(acc, g[q*4 + iq*2 + jq]);
    }
    K[tid] = acc;
}

// ---- 3. complex GEMM  C = A * perm_rows(B) ---------------------------------
__global__ __launch_bounds__(256) void gemm_pb(float2* __restrict__ C,
                                               const float2* __restrict__ A,
                                               const float2* __restrict__ B,
                                               int strideC, int strideA, int strideB) {
    int ch = blockIdx.z;
    const float2* Ac = A + (size_t)ch * strideA;
    const float2* Bc = B + (size_t)ch * strideB;
    float2* Cc = C + (size_t)ch * strideC;
    int jb = blockIdx.x * 32, ib = blockIdx.y * 32;
    int t = threadIdx.x;
    int tx = t & 15, ty = t >> 4;
    __shared__ float2 As[32][33], Bs[32][33];
    float2 a00={0,0}, a01={0,0}, a10={0,0}, a11={0,0};
    for (int kb = 0; kb < 256; kb += 32) {
        __syncthreads();
        #pragma unroll
        for (int e2 = 0; e2 < 4; ++e2) {
            int idx = t + e2*256; int r = idx >> 5, cc = idx & 31;
            As[r][cc] = Ac[(ib + r)*256 + kb + cc];
            Bs[r][cc] = Bc[rho(kb + r)*256 + jb + cc];
        }
        __syncthreads();
        #pragma unroll
        for (int kk = 0; kk < 32; ++kk) {
            float2 x0 = As[ty*2][kk], x1 = As[ty*2+1][kk];
            float2 y0 = Bs[kk][tx*2], y1 = Bs[kk][tx*2+1];
            cmac(a00, x0, y0); cmac(a01, x0, y1);
            cmac(a10, x1, y0); cmac(a11, x1, y1);
        }
    }
    Cc[(ib+ty*2  )*256 + jb+tx*2  ] = a00;
    Cc[(ib+ty*2  )*256 + jb+tx*2+1] = a01;
    Cc[(ib+ty*2+1)*256 + jb+tx*2  ] = a10;
    Cc[(ib+ty*2+1)*256 + jb+tx*2+1] = a11;
}

// fragment-order scatter for mfma_f32_16x16x32 A-operand:
// lane l holds M[itile*16 + (l&15)][ks*32 + (l>>4)*8 + jj], 8 contiguous fp16.
__device__ __forceinline__ void store_frag(_Float16* Mf, int i, int j, float v) {
    int t = i >> 4, r = i & 15;
    int ks = j >> 5, kk = j & 31;
    int q = kk >> 3, jj = kk & 7;
    Mf[(size_t)(((t*8 + ks)*64) + q*16 + r)*8 + jj] = (_Float16)v;
}

// ---- 4. M[i][j] = sum_k sign(k) Re( conj(W[rho(k)][i]) W[rho(k)][j] ), fp16 frag order
__global__ __launch_bounds__(256) void build_M(_Float16* __restrict__ Mf,
                                               const float2* __restrict__ W) {
    int ch = blockIdx.z;
    const float2* Wc = W + (size_t)ch * 65536;
    _Float16* Mc = Mf + (size_t)ch * 65536;
    int jb = blockIdx.x * 32, ib = blockIdx.y * 32;
    int t = threadIdx.x;
    int tx = t & 15, ty = t >> 4;
    __shared__ float2 WsI[32][33], WsJ[32][33];
    float a00=0, a01=0, a10=0, a11=0;
    for (int kb = 0; kb < 256; kb += 32) {
        __syncthreads();
        #pragma unroll
        for (int e2 = 0; e2 < 4; ++e2) {
            int idx = t + e2*256; int r = idx >> 5, cc = idx & 31;
            int krow = rho(kb + r);
            float sgn = ((kb + r) & 128) ? -1.f : 1.f;
            float2 wi = Wc[krow*256 + ib + cc];
            WsI[r][cc] = make_float2(wi.x*sgn, wi.y*sgn);
            WsJ[r][cc] = Wc[krow*256 + jb + cc];
        }
        __syncthreads();
        #pragma unroll
        for (int kk = 0; kk < 32; ++kk) {
            float2 i0 = WsI[kk][ty*2], i1 = WsI[kk][ty*2+1];
            float2 j0 = WsJ[kk][tx*2], j1 = WsJ[kk][tx*2+1];
            a00 = fmaf(i0.x, j0.x, fmaf(i0.y, j0.y, a00));
            a01 = fmaf(i0.x, j1.x, fmaf(i0.y, j1.y, a01));
            a10 = fmaf(i1.x, j0.x, fmaf(i1.y, j0.y, a10));
            a11 = fmaf(i1.x, j1.x, fmaf(i1.y, j1.y, a11));
        }
    }
    store_frag(Mc, ib+ty*2,   jb+tx*2,   a00);
    store_frag(Mc, ib+ty*2,   jb+tx*2+1, a01);
    store_frag(Mc, ib+ty*2+1, jb+tx*2,   a10);
    store_frag(Mc, ib+ty*2+1, jb+tx*2+1, a11);
}

// ---- 5. patch extraction + normalization -> fp16, zero-padded to PTOT ------
__global__ __launch_bounds__(256) void extract(const float* __restrict__ x,
                                               _Float16* __restrict__ sGh) {
    int p = blockIdx.x;           // 0..PTOT-1
    int k = threadIdx.x;          // 0..255
    if (p >= NPATCH) { sGh[(size_t)p*256 + k] = (_Float16)0.f; return; }
    int b = p / (OH*OW); int r = p % (OH*OW);
    int oi = r / OW, oj = r % OW;
    int ci = k >> 4, fi = (k >> 2) & 3, fj = k & 3;
    float v = x[(((size_t)(b*16 + ci))*64 + (oi*2 + fi))*64 + (oj*2 + fj)];
    float ss = v * v;
    #pragma unroll
    for (int m = 1; m < 64; m <<= 1) ss += __shfl_xor(ss, m, 64);
    __shared__ float wsum[4];
    if ((k & 63) == 0) wsum[k >> 6] = ss;
    __syncthreads();
    float tot = wsum[0] + wsum[1] + wsum[2] + wsum[3];
    float inv = tot > 0.f ? 1.f / sqrtf(tot) : 0.f;
    sGh[(size_t)p*256 + k] = (_Float16)(v * inv);
}

// ---- 6. fused MFMA quadform: out[p,c] = s_p^T M_c s_p + bias[c] ------------
// block: 512 thr = 8 waves; each wave owns 64 patches (4 ptiles of 16).
// M_c staged once in LDS (128 KB, fragment order, conflict-free b128 reads).
__global__ __launch_bounds__(512, 2) void fusedqf(const _Float16* __restrict__ sGh,
                                                  const _Float16* __restrict__ Mf,
                                                  const float* __restrict__ bias,
                                                  float* __restrict__ out) {
    extern __shared__ _Float16 Mlds[];      // 65536 halves = 128 KB
    const int tid  = threadIdx.x;
    const int lane = tid & 63;
    const int wv   = tid >> 6;
    const int c    = blockIdx.y;
    const int p0   = blockIdx.x * PT_BLK + wv * 64;

    const _Float16* Msrc = Mf + (size_t)c * 65536;

    // stage M (linear copy, coalesced 16B/lane, conflict-free ds_write_b128)
    #pragma unroll
    for (int it = 0; it < 16; ++it) {
        int vi = it * 512 + tid;            // f16x8 index
        ((f16x8*)Mlds)[vi] = ((const f16x8*)Msrc)[vi];
    }

    // preload B fragments: lane holds s[p0+pt*16+(lane&15)][ks*32+(lane>>4)*8 .. +8]
    f16x8 bfrag[4][8];
    const int prow = lane & 15, kq = lane >> 4;
    #pragma unroll
    for (int pt = 0; pt < 4; ++pt) {
        const _Float16* srow = sGh + (size_t)(p0 + pt*16 + prow) * 256 + kq*8;
        #pragma unroll
        for (int ks = 0; ks < 8; ++ks)
            bfrag[pt][ks] = *(const f16x8*)(srow + ks*32);
    }

    __syncthreads();

    float o0 = 0.f, o1 = 0.f, o2 = 0.f, o3 = 0.f;
    const f16x8* Mv = (const f16x8*)Mlds;

    #pragma unroll 2
    for (int t = 0; t < 16; ++t) {
        f32x4 a0 = {0,0,0,0}, a1 = {0,0,0,0}, a2 = {0,0,0,0}, a3 = {0,0,0,0};
        #pragma unroll
        for (int ks = 0; ks < 8; ++ks) {
            f16x8 a = Mv[(t*8 + ks)*64 + lane];
            a0 = __builtin_amdgcn_mfma_f32_16x16x32_f16(a, bfrag[0][ks], a0, 0, 0, 0);
            a1 = __builtin_amdgcn_mfma_f32_16x16x32_f16(a, bfrag[1][ks], a1, 0, 0, 0);
            a2 = __builtin_amdgcn_mfma_f32_16x16x32_f16(a, bfrag[2][ks], a2, 0, 0, 0);
            a3 = __builtin_amdgcn_mfma_f32_16x16x32_f16(a, bfrag[3][ks], a3, 0, 0, 0);
        }
        // fold Y tile into out: lane rows i = t*16 + kq*4 + r, col p = prow
        int ioff = t*16 + kq*4;
        {
            f16x4 sv = *(const f16x4*)(sGh + (size_t)(p0 + 0*16 + prow)*256 + ioff);
            o0 += (float)sv[0]*a0[0] + (float)sv[1]*a0[1] + (float)sv[2]*a0[2] + (float)sv[3]*a0[3];
        }
        {
            f16x4 sv = *(const f16x4*)(sGh + (size_t)(p0 + 1*16 + prow)*256 + ioff);
            o1 += (float)sv[0]*a1[0] + (float)sv[1]*a1[1] + (float)sv[2]*a1[2] + (float)sv[3]*a1[3];
        }
        {
            f16x4 sv = *(const f16x4*)(sGh + (size_t)(p0 + 2*16 + prow)*256 + ioff);
            o2 += (float)sv[0]*a2[0] + (float)sv[1]*a2[1] + (float)sv[2]*a2[2] + (float)sv[3]*a2[3];
        }
        {
            f16x4 sv = *(const f16x4*)(sGh + (size_t)(p0 + 3*16 + prow)*256 + ioff);
            o3 += (float)sv[0]*a3[0] + (float)sv[1]*a3[1] + (float)sv[2]*a3[2] + (float)sv[3]*a3[3];
        }
    }

    // reduce across the 4 row-quarters (lanes p, p+16, p+32, p+48)
    float ov[4] = {o0, o1, o2, o3};
    float bc = bias[c];
    #pragma unroll
    for (int pt = 0; pt < 4; ++pt) {
        float v = ov[pt];
        v += __shfl_xor(v, 16, 64);
        v += __shfl_xor(v, 32, 64);
        if (kq == 0) {
            int p = p0 + pt*16 + prow;
            if (p < NPATCH) {
                int b = p / (OH*OW); int r2 = p % (OH*OW);
                int oi = r2 / OW, oj = r2 % OW;
                out[(((size_t)(b*COUT + c))*OH + oi)*OW + oj] = v + bc;
            }
        }
    }
}

extern "C" void kernel_launch(void* const* d_in, const int* in_sizes, int n_in,
                              void* d_out, int out_size, void* d_ws, size_t ws_size,
                              hipStream_t stream) {
    const float* x    = (const float*)d_in[0];
    const float* w    = (const float*)d_in[1];
    const float* bias = (const float*)d_in[2];
    float* out = (float*)d_out;

    // workspace layout (bytes)
    const size_t OFF_GATES = 0;                          //   6144 (pad 8192)
    const size_t OFF_K     = 8192;                       // 24*65536*8 = 12,582,912
    const size_t OFF_T1    = OFF_K  + 12582912;          //  4,194,304
    const size_t OFF_T2    = OFF_T1 + 4194304;           //  4,194,304
    const size_t OFF_MH    = OFF_T2 + 4194304;           //  8*65536*2 = 1,048,576
    const size_t OFF_SGH   = OFF_MH + 1048576;           // 31232*256*2 = 15,990,784
    const size_t TOTAL     = OFF_SGH + 15990784;
    if (ws_size < TOTAL) return;

    char* ws = (char*)d_ws;
    float2*    gates = (float2*)(ws + OFF_GATES);
    float2*    K     = (float2*)(ws + OFF_K);
    float2*    T1    = (float2*)(ws + OFF_T1);
    float2*    T2    = (float2*)(ws + OFF_T2);
    _Float16*  Mh    = (_Float16*)(ws + OFF_MH);
    _Float16*  sGh   = (_Float16*)(ws + OFF_SGH);

    prep_gates<<<1, 256, 0, stream>>>(w, gates);
    build_K<<<(COUT*LAYERS*65536)/256, 256, 0, stream>>>(gates, K);
    gemm_pb<<<dim3(8,8,COUT), 256, 0, stream>>>(T1, K + 65536, K, 65536, 3*65536, 3*65536);
    gemm_pb<<<dim3(8,8,COUT), 256, 0, stream>>>(T2, K + 2*65536, T1, 65536, 3*65536, 65536);
    build_M<<<dim3(8,8,COUT), 256, 0, stream>>>(Mh, T2);
    extract<<<PTOT, 256, 0, stream>>>(x, sGh);
    fusedqf<<<dim3(NTILE, COUT), 512, 131072, stream>>>(sGh, Mh, bias, out);
}

// Round 3
// 97.948 us; speedup vs baseline: 6.5357x; 1.6955x over previous
//
#include <hip/hip_runtime.h>
#include <math.h>

#define NQ     8
#define DIM    256
#define LAYERS 3
#define COUT   8
#define NB     32
#define OH     31
#define OW     31
#define NPATCH (NB*OH*OW)     // 30752
#define PT_BLK 512
#define NTILE  64             // padded so NTILE*COUT = 512 blocks, XCD-bijective
#define PTOT   (NTILE*PT_BLK) // 32768
#define NPAIR  72             // packed upper-tri (t,ks) pairs
#define MPACK  (NPAIR*64*8)   // 36864 halves per channel

typedef _Float16 f16x8 __attribute__((ext_vector_type(8)));
typedef _Float16 f16x4 __attribute__((ext_vector_type(4)));
typedef float    f32x4 __attribute__((ext_vector_type(4)));

__device__ __forceinline__ float2 cmul(float2 a, float2 b) {
    return make_float2(a.x*b.x - a.y*b.y, a.x*b.y + a.y*b.x);
}
__device__ __forceinline__ float2 cadd(float2 a, float2 b) {
    return make_float2(a.x + b.x, a.y + b.y);
}

// CNOT-ring permutation (verified round 1)
__device__ __forceinline__ int rho(int i) {
    #pragma unroll
    for (int q = 7; q >= 0; --q) {
        int t = (q + 1) & 7;
        if ((i >> (7 - q)) & 1) i ^= 1 << (7 - t);
    }
    return i;
}

// packed pair offsets: off(t) = sum_{t'<t} (8 - (t'>>1))
__device__ __constant__ int OFFT[16] = {0,8,16,23,30,36,42,47,52,56,60,63,66,68,70,71};

// ---- 1. per-(c,l,q) 2x2 rotation matrices ----------------------------------
__global__ void prep_gates(const float* __restrict__ w, float2* __restrict__ gates) {
    int tid = blockIdx.x * blockDim.x + threadIdx.x;
    if (tid >= COUT * LAYERS * NQ) return;
    float phi = w[tid*3+0], th = w[tid*3+1], om = w[tid*3+2];
    float cth = cosf(th * 0.5f), sth = sinf(th * 0.5f);
    float a = 0.5f * (phi + om), b = 0.5f * (phi - om);
    float sa, ca, sb, cb;
    sincosf(a, &sa, &ca);
    sincosf(b, &sb, &cb);
    gates[tid*4+0] = make_float2( cth*ca, -cth*sa);
    gates[tid*4+1] = make_float2(-sth*cb, -sth*sb);
    gates[tid*4+2] = make_float2( sth*cb, -sth*sb);
    gates[tid*4+3] = make_float2( cth*ca,  cth*sa);
}

// ---- 2. build W columns: col j of U = P K2 P K1 P K0, emit fp16 operands ---
// At[ch][j][k'] = sgn(k) * {Re,Im} W[k][j]   (A operand, sign folded)
// Bt[ch][j][k'] =           {Re,Im} W[k][j]  (B operand)
__global__ __launch_bounds__(256) void build_W(const float2* __restrict__ gates,
                                               _Float16* __restrict__ At,
                                               _Float16* __restrict__ Bt) {
    const int j  = blockIdx.x;      // column 0..255
    const int ch = blockIdx.y;
    const int i  = threadIdx.x;     // row 0..255
    __shared__ float2 g[96];        // 3 layers x 8 qubits x 4 entries
    __shared__ float2 v[256];
    if (i < 96) g[i] = gates[ch*96 + i];
    __syncthreads();

    // initial: column j of K0 (Kron element product)
    float2 acc = make_float2(1.f, 0.f);
    #pragma unroll
    for (int q = 0; q < 8; ++q) {
        int iq = (i >> (7 - q)) & 1, jq = (j >> (7 - q)) & 1;
        acc = cmul(acc, g[q*4 + iq*2 + jq]);
    }
    v[i] = acc;
    __syncthreads();

    #pragma unroll
    for (int l = 1; l < 3; ++l) {
        // P
        float2 a = v[rho(i)];
        __syncthreads();
        v[i] = a;
        __syncthreads();
        // 8 single-qubit gates
        #pragma unroll
        for (int q = 0; q < 8; ++q) {
            int bit = 1 << (7 - q);
            float2 m00 = g[(l*8+q)*4+0], m01 = g[(l*8+q)*4+1];
            float2 m10 = g[(l*8+q)*4+2], m11 = g[(l*8+q)*4+3];
            float2 x = v[i], y = v[i ^ bit];
            __syncthreads();
            float2 nv = (i & bit) ? cadd(cmul(m10, y), cmul(m11, x))
                                  : cadd(cmul(m00, x), cmul(m01, y));
            v[i] = nv;
            __syncthreads();
        }
    }
    // final P, then emit
    float2 a = v[rho(i)];
    float sgn = (i & 128) ? -1.f : 1.f;
    size_t row = ((size_t)ch*256 + j) * 512;
    At[row + i]       = (_Float16)(sgn * a.x);
    At[row + 256 + i] = (_Float16)(sgn * a.y);
    Bt[row + i]       = (_Float16)a.x;
    Bt[row + 256 + i] = (_Float16)a.y;
}

// ---- 3. M' = upper-tri-doubled (A^T D A), K=512 fp16 MFMA, packed frag out -
__global__ __launch_bounds__(256) void build_Mp(const _Float16* __restrict__ At,
                                                const _Float16* __restrict__ Bt,
                                                _Float16* __restrict__ Mp) {
    const int ch = blockIdx.z;
    const int ti = blockIdx.y;                       // 0..15
    const int wv = threadIdx.x >> 6;
    const int jt = blockIdx.x * 4 + wv;              // 0..15
    const int jt0 = 2 * (ti >> 1);
    if (jt < jt0) return;
    const int lane = threadIdx.x & 63;
    const int c16 = lane & 15, kq = lane >> 4;
    const int pidx = OFFT[ti] + (jt >> 1) - (ti >> 1);
    _Float16* Mc = Mp + (size_t)ch * MPACK;

    f32x4 acc = {0.f, 0.f, 0.f, 0.f};
    if (jt >= ti) {
        const _Float16* Ar = At + ((size_t)ch*256 + ti*16 + c16) * 512 + kq*8;
        const _Float16* Br = Bt + ((size_t)ch*256 + jt*16 + c16) * 512 + kq*8;
        #pragma unroll
        for (int kk = 0; kk < 16; ++kk) {
            f16x8 af = *(const f16x8*)(Ar + kk*32);
            f16x8 bf = *(const f16x8*)(Br + kk*32);
            acc = __builtin_amdgcn_mfma_f32_16x16x32_f16(af, bf, acc, 0, 0, 0);
        }
    }
    int w = (jt & 1) * 16 + c16;
    int kqp = w >> 3, jj = w & 7;
    #pragma unroll
    for (int reg = 0; reg < 4; ++reg) {
        int i_g = ti*16 + kq*4 + reg;
        int j_g = jt*16 + c16;
        float val = (jt >= ti) ? acc[reg] : 0.f;
        val *= (j_g > i_g) ? 2.f : ((j_g == i_g) ? 1.f : 0.f);
        Mc[(size_t)((pidx*64 + kqp*16 + (kq*4 + reg)) * 8 + jj)] = (_Float16)val;
    }
}

// ---- 4. patch extraction + normalization -> fp16, zero-padded to PTOT ------
__global__ __launch_bounds__(256) void extract(const float* __restrict__ x,
                                               _Float16* __restrict__ sGh) {
    int wv = threadIdx.x >> 6, lane = threadIdx.x & 63;
    int p = blockIdx.x * 4 + wv;
    if (p >= NPATCH) {
        f16x4 z = {0,0,0,0};
        *(f16x4*)&sGh[(size_t)p*256 + lane*4] = z;
        return;
    }
    int b = p / (OH*OW); int r = p % (OH*OW);
    int oi = r / OW, oj = r % OW;
    int ci = lane >> 2, fi = lane & 3;
    const float* xb = x + (((size_t)(b*16 + ci))*64 + (oi*2 + fi))*64 + oj*2;
    float2 v01 = *(const float2*)xb;
    float2 v23 = *(const float2*)(xb + 2);
    float ss = v01.x*v01.x + v01.y*v01.y + v23.x*v23.x + v23.y*v23.y;
    #pragma unroll
    for (int m = 1; m < 64; m <<= 1) ss += __shfl_xor(ss, m, 64);
    float inv = ss > 0.f ? 1.f / sqrtf(ss) : 0.f;
    f16x4 o;
    o[0] = (_Float16)(v01.x*inv); o[1] = (_Float16)(v01.y*inv);
    o[2] = (_Float16)(v23.x*inv); o[3] = (_Float16)(v23.y*inv);
    *(f16x4*)&sGh[(size_t)p*256 + lane*4] = o;
}

// ---- 5. fused MFMA quadform: out[p,c] = s_p^T M'_c s_p + bias[c] -----------
// 512 blocks, XCD-pinned: tile group fixed per XCD, all 8 channels hit same sG.
__global__ __launch_bounds__(512, 2) void fusedqf(const _Float16* __restrict__ sGh,
                                                  const _Float16* __restrict__ Mp,
                                                  const float* __restrict__ bias,
                                                  float* __restrict__ out) {
    extern __shared__ _Float16 Mlds[];      // 36864 halves = 72 KB
    const int id   = blockIdx.x;
    const int xcd  = id & 7;
    const int g    = id >> 3;
    const int c    = g >> 3;
    const int tile = (g & 7) * 8 + xcd;
    const int tid  = threadIdx.x;
    const int lane = tid & 63;
    const int wv   = tid >> 6;
    const int p0   = tile * PT_BLK + wv * 64;

    const _Float16* Msrc = Mp + (size_t)c * MPACK;
    #pragma unroll
    for (int it = 0; it < 9; ++it) {
        int vi = it * 512 + tid;            // 4608 f16x8 vectors
        ((f16x8*)Mlds)[vi] = ((const f16x8*)Msrc)[vi];
    }

    // preload B fragments: lane holds s[p0+pt*16+prow][ks*32+kq*8 .. +8]
    f16x8 bfrag[4][8];
    const int prow = lane & 15, kq = lane >> 4;
    #pragma unroll
    for (int pt = 0; pt < 4; ++pt) {
        const _Float16* srow = sGh + (size_t)(p0 + pt*16 + prow) * 256 + kq*8;
        #pragma unroll
        for (int ks = 0; ks < 8; ++ks)
            bfrag[pt][ks] = *(const f16x8*)(srow + ks*32);
    }

    __syncthreads();

    float o0 = 0.f, o1 = 0.f, o2 = 0.f, o3 = 0.f;
    const f16x8* Mv = (const f16x8*)Mlds;

    #pragma unroll
    for (int t = 0; t < 16; ++t) {
        f32x4 a0 = {0,0,0,0}, a1 = {0,0,0,0}, a2 = {0,0,0,0}, a3 = {0,0,0,0};
        #pragma unroll
        for (int ks = (t >> 1); ks < 8; ++ks) {
            int pidx = OFFT[t] + ks - (t >> 1);
            f16x8 a = Mv[pidx*64 + lane];
            a0 = __builtin_amdgcn_mfma_f32_16x16x32_f16(a, bfrag[0][ks], a0, 0, 0, 0);
            a1 = __builtin_amdgcn_mfma_f32_16x16x32_f16(a, bfrag[1][ks], a1, 0, 0, 0);
            a2 = __builtin_amdgcn_mfma_f32_16x16x32_f16(a, bfrag[2][ks], a2, 0, 0, 0);
            a3 = __builtin_amdgcn_mfma_f32_16x16x32_f16(a, bfrag[3][ks], a3, 0, 0, 0);
        }
        int ioff = t*16 + kq*4;
        {
            f16x4 sv = *(const f16x4*)(sGh + (size_t)(p0 + 0*16 + prow)*256 + ioff);
            o0 += (float)sv[0]*a0[0] + (float)sv[1]*a0[1] + (float)sv[2]*a0[2] + (float)sv[3]*a0[3];
        }
        {
            f16x4 sv = *(const f16x4*)(sGh + (size_t)(p0 + 1*16 + prow)*256 + ioff);
            o1 += (float)sv[0]*a1[0] + (float)sv[1]*a1[1] + (float)sv[2]*a1[2] + (float)sv[3]*a1[3];
        }
        {
            f16x4 sv = *(const f16x4*)(sGh + (size_t)(p0 + 2*16 + prow)*256 + ioff);
            o2 += (float)sv[0]*a2[0] + (float)sv[1]*a2[1] + (float)sv[2]*a2[2] + (float)sv[3]*a2[3];
        }
        {
            f16x4 sv = *(const f16x4*)(sGh + (size_t)(p0 + 3*16 + prow)*256 + ioff);
            o3 += (float)sv[0]*a3[0] + (float)sv[1]*a3[1] + (float)sv[2]*a3[2] + (float)sv[3]*a3[3];
        }
    }

    float ov[4] = {o0, o1, o2, o3};
    float bc = bias[c];
    #pragma unroll
    for (int pt = 0; pt < 4; ++pt) {
        float v = ov[pt];
        v += __shfl_xor(v, 16, 64);
        v += __shfl_xor(v, 32, 64);
        if (kq == 0) {
            int p = p0 + pt*16 + prow;
            if (p < NPATCH) {
                int b = p / (OH*OW); int r2 = p % (OH*OW);
                int oi = r2 / OW, oj = r2 % OW;
                out[(((size_t)(b*COUT + c))*OH + oi)*OW + oj] = v + bc;
            }
        }
    }
}

extern "C" void kernel_launch(void* const* d_in, const int* in_sizes, int n_in,
                              void* d_out, int out_size, void* d_ws, size_t ws_size,
                              hipStream_t stream) {
    const float* x    = (const float*)d_in[0];
    const float* w    = (const float*)d_in[1];
    const float* bias = (const float*)d_in[2];
    float* out = (float*)d_out;

    const size_t OFF_GATES = 0;                            //  6144 (pad 8192)
    const size_t OFF_AT    = 8192;                         //  8*256*512*2 = 2,097,152
    const size_t OFF_BT    = OFF_AT  + 2097152;            //  2,097,152
    const size_t OFF_MP    = OFF_BT  + 2097152;            //  8*36864*2 = 589,824
    const size_t OFF_SGH   = OFF_MP  + 589824;             //  32768*256*2 = 16,777,216
    const size_t TOTAL     = OFF_SGH + 16777216;
    if (ws_size < TOTAL) return;

    char* ws = (char*)d_ws;
    float2*    gates = (float2*)(ws + OFF_GATES);
    _Float16*  At    = (_Float16*)(ws + OFF_AT);
    _Float16*  Bt    = (_Float16*)(ws + OFF_BT);
    _Float16*  Mp    = (_Float16*)(ws + OFF_MP);
    _Float16*  sGh   = (_Float16*)(ws + OFF_SGH);

    prep_gates<<<1, 256, 0, stream>>>(w, gates);
    build_W<<<dim3(256, COUT), 256, 0, stream>>>(gates, At, Bt);
    build_Mp<<<dim3(4, 16, COUT), 256, 0, stream>>>(At, Bt, Mp);
    extract<<<PTOT/4, 256, 0, stream>>>(x, sGh);
    fusedqf<<<NTILE*COUT, 512, NPAIR*64*8*sizeof(_Float16), stream>>>(sGh, Mp, bias, out);
}

// Round 4
// 62.244 us; speedup vs baseline: 10.2847x; 1.5736x over previous
//
#include <hip/hip_runtime.h>
#include <math.h>

#define NQ     8
#define DIM    256
#define LAYERS 3
#define COUT   8
#define NB     32
#define OH     31
#define OW     31
#define NPATCH (NB*OH*OW)     // 30752
#define PT_BLK 512
#define NTILE  64             // 64 tiles x 8 ch = 512 blocks, XCD-bijective
#define PTOT   (NTILE*PT_BLK) // 32768
#define NPTILE (PTOT/16)      // 2048 16-patch groups
#define NPAIR  72             // packed upper-tri (t,ks) pairs
#define MPACK  (NPAIR*64*8)   // 36864 halves per channel

typedef _Float16 f16x8 __attribute__((ext_vector_type(8)));
typedef _Float16 f16x4 __attribute__((ext_vector_type(4)));
typedef float    f32x4 __attribute__((ext_vector_type(4)));

__device__ __forceinline__ float2 cmul(float2 a, float2 b) {
    return make_float2(a.x*b.x - a.y*b.y, a.x*b.y + a.y*b.x);
}
__device__ __forceinline__ float2 cadd(float2 a, float2 b) {
    return make_float2(a.x + b.x, a.y + b.y);
}

// CNOT-ring permutation (verified round 1)
__device__ __forceinline__ int rho(int i) {
    #pragma unroll
    for (int q = 7; q >= 0; --q) {
        int t = (q + 1) & 7;
        if ((i >> (7 - q)) & 1) i ^= 1 << (7 - t);
    }
    return i;
}

// ---- 1. build W columns (gates computed in-block): col j of U = P K2 P K1 P K0
// At[ch][j][k'] = sgn(k) * {Re,Im} W[k][j]   (A operand, sign folded)
// Bt[ch][j][k'] =           {Re,Im} W[k][j]  (B operand)
__global__ __launch_bounds__(256) void build_W(const float* __restrict__ w,
                                               _Float16* __restrict__ At,
                                               _Float16* __restrict__ Bt) {
    const int j  = blockIdx.x;      // column 0..255
    const int ch = blockIdx.y;
    const int i  = threadIdx.x;     // row 0..255
    __shared__ float2 g[96];        // 24 gates x 4 entries
    __shared__ float2 v[256];
    if (i < 24) {
        const float* wp = w + (ch*24 + i)*3;
        float phi = wp[0], th = wp[1], om = wp[2];
        float cth = cosf(th * 0.5f), sth = sinf(th * 0.5f);
        float a = 0.5f * (phi + om), b = 0.5f * (phi - om);
        float sa, ca, sb, cb;
        sincosf(a, &sa, &ca);
        sincosf(b, &sb, &cb);
        g[i*4+0] = make_float2( cth*ca, -cth*sa);
        g[i*4+1] = make_float2(-sth*cb, -sth*sb);
        g[i*4+2] = make_float2( sth*cb, -sth*sb);
        g[i*4+3] = make_float2( cth*ca,  cth*sa);
    }
    __syncthreads();

    // initial: column j of K0 (Kron element product)
    float2 acc = make_float2(1.f, 0.f);
    #pragma unroll
    for (int q = 0; q < 8; ++q) {
        int iq = (i >> (7 - q)) & 1, jq = (j >> (7 - q)) & 1;
        acc = cmul(acc, g[q*4 + iq*2 + jq]);
    }
    v[i] = acc;
    __syncthreads();

    #pragma unroll
    for (int l = 1; l < 3; ++l) {
        // P
        float2 a = v[rho(i)];
        __syncthreads();
        v[i] = a;
        __syncthreads();
        // 8 single-qubit gates
        #pragma unroll
        for (int q = 0; q < 8; ++q) {
            int bit = 1 << (7 - q);
            float2 m00 = g[(l*8+q)*4+0], m01 = g[(l*8+q)*4+1];
            float2 m10 = g[(l*8+q)*4+2], m11 = g[(l*8+q)*4+3];
            float2 x = v[i], y = v[i ^ bit];
            __syncthreads();
            float2 nv = (i & bit) ? cadd(cmul(m10, y), cmul(m11, x))
                                  : cadd(cmul(m00, x), cmul(m01, y));
            v[i] = nv;
            __syncthreads();
        }
    }
    // final P, then emit
    float2 a = v[rho(i)];
    float sgn = (i & 128) ? -1.f : 1.f;
    size_t row = ((size_t)ch*256 + j) * 512;
    At[row + i]       = (_Float16)(sgn * a.x);
    At[row + 256 + i] = (_Float16)(sgn * a.y);
    Bt[row + i]       = (_Float16)a.x;
    Bt[row + 256 + i] = (_Float16)a.y;
}

// ---- 2. M' = upper-tri-doubled (A^T D A), K=512 fp16 MFMA, packed frag out -
__global__ __launch_bounds__(256) void build_Mp(const _Float16* __restrict__ At,
                                                const _Float16* __restrict__ Bt,
                                                _Float16* __restrict__ Mp) {
    const int ch = blockIdx.z;
    const int ti = blockIdx.y;                       // 0..15
    const int wv = threadIdx.x >> 6;
    const int jt = blockIdx.x * 4 + wv;              // 0..15
    const int jt0 = 2 * (ti >> 1);
    if (jt < jt0) return;
    const int lane = threadIdx.x & 63;
    const int c16 = lane & 15, kq = lane >> 4;
    // OFFT[t] = 8t - 2*((t>>1)*((t>>1)-1)/2) - ... use running formula via small table
    const int OFFT[16] = {0,8,16,23,30,36,42,47,52,56,60,63,66,68,70,71};
    const int pidx = OFFT[ti] + (jt >> 1) - (ti >> 1);
    _Float16* Mc = Mp + (size_t)ch * MPACK;

    f32x4 acc = {0.f, 0.f, 0.f, 0.f};
    if (jt >= ti) {
        const _Float16* Ar = At + ((size_t)ch*256 + ti*16 + c16) * 512 + kq*8;
        const _Float16* Br = Bt + ((size_t)ch*256 + jt*16 + c16) * 512 + kq*8;
        #pragma unroll
        for (int kk = 0; kk < 16; ++kk) {
            f16x8 af = *(const f16x8*)(Ar + kk*32);
            f16x8 bf = *(const f16x8*)(Br + kk*32);
            acc = __builtin_amdgcn_mfma_f32_16x16x32_f16(af, bf, acc, 0, 0, 0);
        }
    }
    int wsel = (jt & 1) * 16 + c16;
    int kqp = wsel >> 3, jj = wsel & 7;
    #pragma unroll
    for (int reg = 0; reg < 4; ++reg) {
        int i_g = ti*16 + kq*4 + reg;
        int j_g = jt*16 + c16;
        float val = (jt >= ti) ? acc[reg] : 0.f;
        val *= (j_g > i_g) ? 2.f : ((j_g == i_g) ? 1.f : 0.f);
        Mc[(size_t)((pidx*64 + kqp*16 + (kq*4 + reg)) * 8 + jj)] = (_Float16)val;
    }
}

// ---- 3. patch extraction + normalization -> fp16 in B-FRAGMENT order -------
// sF layout: [ptile][ks 0..7][lane 0..63][j 0..7]; lane=(kq<<4)|prow,
// holding s[ptile*16+prow][ks*32 + kq*8 + j].
__global__ __launch_bounds__(256) void extract(const float* __restrict__ x,
                                               _Float16* __restrict__ sF) {
    const int tb  = blockIdx.x;          // ptile 0..NPTILE-1
    const int tid = threadIdx.x;
    const int wv  = tid >> 6, lane = tid & 63;
    __shared__ _Float16 sT[16][264];     // +8 halves pad -> 2-way banks (free)

    #pragma unroll
    for (int pp = 0; pp < 4; ++pp) {
        int pl = wv*4 + pp;
        int p  = tb*16 + pl;
        float2 v01 = make_float2(0.f,0.f), v23 = make_float2(0.f,0.f);
        if (p < NPATCH) {
            int b = p / (OH*OW); int r = p % (OH*OW);
            int oi = r / OW, oj = r % OW;
            int ci = lane >> 2, fi = lane & 3;
            const float* xb = x + (((size_t)(b*16 + ci))*64 + (oi*2 + fi))*64 + oj*2;
            v01 = *(const float2*)xb;
            v23 = *(const float2*)(xb + 2);
        }
        float ss = v01.x*v01.x + v01.y*v01.y + v23.x*v23.x + v23.y*v23.y;
        #pragma unroll
        for (int m = 1; m < 64; m <<= 1) ss += __shfl_xor(ss, m, 64);
        float inv = ss > 0.f ? 1.f / sqrtf(ss) : 0.f;
        f16x4 o;
        o[0] = (_Float16)(v01.x*inv); o[1] = (_Float16)(v01.y*inv);
        o[2] = (_Float16)(v23.x*inv); o[3] = (_Float16)(v23.y*inv);
        *(f16x4*)&sT[pl][lane*4] = o;
    }
    __syncthreads();

    #pragma unroll
    for (int e = 0; e < 2; ++e) {
        int vi = tid + e*256;            // 0..511
        int ks = vi >> 6, ln = vi & 63;
        int kq = ln >> 4, prow = ln & 15;
        f16x8 o = *(const f16x8*)&sT[prow][ks*32 + kq*8];
        ((f16x8*)sF)[(size_t)tb*512 + vi] = o;
    }
}

// ---- 4. fused MFMA quadform: out[p,c] = s_p^T M'_c s_p + bias[c] -----------
// 512 blocks XCD-pinned; 8 waves x 64 patches. M' (72KB) in LDS.
// amdgpu_waves_per_eu(2,2): force 256-VGPR budget (bfrag[4][8]=128 VGPR must
// stay in registers -- round-3's 48MB scratch traffic came from capping at 128).
__global__ __attribute__((amdgpu_flat_work_group_size(512,512), amdgpu_waves_per_eu(2,2)))
void fusedqf(const _Float16* __restrict__ sF,
             const _Float16* __restrict__ Mp,
             const float* __restrict__ bias,
             float* __restrict__ out) {
    extern __shared__ _Float16 Mlds[];      // 36864 halves = 72 KB
    const int id   = blockIdx.x;
    const int xcd  = id & 7;
    const int g    = id >> 3;
    const int c    = g >> 3;
    const int tile = (g & 7) * 8 + xcd;
    const int tid  = threadIdx.x;
    const int lane = tid & 63;
    const int wv   = tid >> 6;
    const int prow = lane & 15, kq = lane >> 4;
    const int tp0  = tile*32 + wv*4;        // base ptile (of 16 patches)

    // stage M' (linear, coalesced)
    const _Float16* Msrc = Mp + (size_t)c * MPACK;
    #pragma unroll
    for (int it = 0; it < 9; ++it) {
        int vi = it * 512 + tid;
        ((f16x8*)Mlds)[vi] = ((const f16x8*)Msrc)[vi];
    }

    // preload B fragments (coalesced b128 from fragment-order sF)
    f16x8 bfrag[4][8];
    #pragma unroll
    for (int pt = 0; pt < 4; ++pt) {
        const f16x8* src = (const f16x8*)sF + (size_t)(tp0 + pt)*512 + lane;
        #pragma unroll
        for (int ks = 0; ks < 8; ++ks)
            bfrag[pt][ks] = src[ks*64];
    }

    __syncthreads();

    // fold-load base: s[p = tp*16+prow][i = t*16 + kq*4 .. +4), addr = base + 256*t halves
    const _Float16* fold0[4];
    #pragma unroll
    for (int pt = 0; pt < 4; ++pt)
        fold0[pt] = sF + ((size_t)(tp0 + pt)*8*64 + (kq>>1)*16 + prow)*8 + (kq&1)*4;

    float o0 = 0.f, o1 = 0.f, o2 = 0.f, o3 = 0.f;
    int pidx = 0;

    #pragma unroll 2
    for (int t = 0; t < 16; ++t) {
        f32x4 a0 = {0,0,0,0}, a1 = {0,0,0,0}, a2 = {0,0,0,0}, a3 = {0,0,0,0};
        #pragma unroll
        for (int ks = 0; ks < 8; ++ks) {
            if (ks >= (t >> 1)) {                     // wave-uniform branch
                f16x8 a = *(const f16x8*)(Mlds + pidx*512 + lane*8);
                a0 = __builtin_amdgcn_mfma_f32_16x16x32_f16(a, bfrag[0][ks], a0, 0, 0, 0);
                a1 = __builtin_amdgcn_mfma_f32_16x16x32_f16(a, bfrag[1][ks], a1, 0, 0, 0);
                a2 = __builtin_amdgcn_mfma_f32_16x16x32_f16(a, bfrag[2][ks], a2, 0, 0, 0);
                a3 = __builtin_amdgcn_mfma_f32_16x16x32_f16(a, bfrag[3][ks], a3, 0, 0, 0);
                ++pidx;
            }
        }
        // fold: o_pt += sum_r s[p][t*16+kq*4+r] * acc[r]
        {
            f16x4 sv = *(const f16x4*)(fold0[0] + t*256);
            o0 += (float)sv[0]*a0[0] + (float)sv[1]*a0[1] + (float)sv[2]*a0[2] + (float)sv[3]*a0[3];
        }
        {
            f16x4 sv = *(const f16x4*)(fold0[1] + t*256);
            o1 += (float)sv[0]*a1[0] + (float)sv[1]*a1[1] + (float)sv[2]*a1[2] + (float)sv[3]*a1[3];
        }
        {
            f16x4 sv = *(const f16x4*)(fold0[2] + t*256);
            o2 += (float)sv[0]*a2[0] + (float)sv[1]*a2[1] + (float)sv[2]*a2[2] + (float)sv[3]*a2[3];
        }
        {
            f16x4 sv = *(const f16x4*)(fold0[3] + t*256);
            o3 += (float)sv[0]*a3[0] + (float)sv[1]*a3[1] + (float)sv[2]*a3[2] + (float)sv[3]*a3[3];
        }
    }

    float ov[4] = {o0, o1, o2, o3};
    float bc = bias[c];
    #pragma unroll
    for (int pt = 0; pt < 4; ++pt) {
        float v = ov[pt];
        v += __shfl_xor(v, 16, 64);
        v += __shfl_xor(v, 32, 64);
        if (kq == 0) {
            int p = (tp0 + pt)*16 + prow;
            if (p < NPATCH) {
                int b = p / (OH*OW); int r2 = p % (OH*OW);
                int oi = r2 / OW, oj = r2 % OW;
                out[(((size_t)(b*COUT + c))*OH + oi)*OW + oj] = v + bc;
            }
        }
    }
}

extern "C" void kernel_launch(void* const* d_in, const int* in_sizes, int n_in,
                              void* d_out, int out_size, void* d_ws, size_t ws_size,
                              hipStream_t stream) {
    const float* x    = (const float*)d_in[0];
    const float* w    = (const float*)d_in[1];
    const float* bias = (const float*)d_in[2];
    float* out = (float*)d_out;

    const size_t OFF_AT  = 0;                       // 8*256*512*2 = 2,097,152
    const size_t OFF_BT  = OFF_AT + 2097152;        // 2,097,152
    const size_t OFF_MP  = OFF_BT + 2097152;        // 8*36864*2 = 589,824
    const size_t OFF_SF  = OFF_MP + 589824;         // 2048*512*16 = 16,777,216
    const size_t TOTAL   = OFF_SF + 16777216;
    if (ws_size < TOTAL) return;

    char* ws = (char*)d_ws;
    _Float16* At = (_Float16*)(ws + OFF_AT);
    _Float16* Bt = (_Float16*)(ws + OFF_BT);
    _Float16* Mp = (_Float16*)(ws + OFF_MP);
    _Float16* sF = (_Float16*)(ws + OFF_SF);

    build_W<<<dim3(256, COUT), 256, 0, stream>>>(w, At, Bt);
    build_Mp<<<dim3(4, 16, COUT), 256, 0, stream>>>(At, Bt, Mp);
    extract<<<NPTILE, 256, 0, stream>>>(x, sF);
    fusedqf<<<NTILE*COUT, 512, MPACK*sizeof(_Float16), stream>>>(sF, Mp, bias, out);
}